// Round 1
// baseline (422.000 us; speedup 1.0000x reference)
//
#include <hip/hip_runtime.h>
#include <math.h>

#define NB 4
#define DD 128
#define HH 128
#define WW 128
#define VOX (DD*HH*WW)          // 2097152 = 2^21
#define NVOX (NB*VOX)           // 8388608

struct GaussW { float w[7]; };

// 1D 7-tap zero-padded convolution along one axis.
// coordinate of the convolved axis = (idx >> shift) & 127; element stride = `stride`.
__global__ void smooth_kernel(const float* __restrict__ in, float* __restrict__ out,
                              GaussW gw, int shift, int stride) {
    int idx = blockIdx.x * blockDim.x + threadIdx.x;
    if (idx >= NVOX) return;
    int c = (idx >> shift) & 127;
    float acc = 0.f;
#pragma unroll
    for (int k = -3; k <= 3; ++k) {
        int cc = c + k;
        if (cc >= 0 && cc < 128) acc += gw.w[k + 3] * in[idx + k * stride];
    }
    out[idx] = acc;
}

// forward diff with duplicated last element (matches jnp.diff + concat(last))
__device__ __forceinline__ float fd(const float* __restrict__ f, int base, int c, int stride) {
    int ip = (c < 127) ? base + stride : base;
    int im = (c < 127) ? base          : base - stride;
    return f[ip] - f[im];
}

// vn = |curl(v)|, v layout (N,3,D,H,W)
__global__ void curlnorm_kernel(const float* __restrict__ v, float* __restrict__ vn) {
    int idx = blockIdx.x * blockDim.x + threadIdx.x;
    if (idx >= NVOX) return;
    int x = idx & 127;
    int y = (idx >> 7) & 127;
    int z = (idx >> 14) & 127;
    int n = idx >> 21;
    const float* u  = v + (size_t)n * 3 * VOX;
    const float* vv = u + VOX;
    const float* w  = vv + VOX;
    int base = idx & (VOX - 1);

    // axes of (N,D,H,W): axis1=D(z, stride 16384), axis2=H(y, stride 128), axis3=W(x, stride 1)
    float cu = fd(w,  base, y, 128)   - fd(vv, base, z, 16384); // dw/dy - dv/dz
    float cv = fd(u,  base, z, 16384) - fd(w,  base, x, 1);     // du/dz - dw/dx
    float cw = fd(vv, base, x, 1)     - fd(u,  base, y, 128);   // dv/dx - du/dy
    vn[idx] = sqrtf(cu * cu + cv * cv + cw * cw);
}

// Per (n,y,x) column: flip along z, cumsum -> transmittance, trapezoid integrate, clip.
__global__ void render_kernel(const float* __restrict__ ds, const float* __restrict__ vn,
                              float* __restrict__ out) {
    int idx = blockIdx.x * blockDim.x + threadIdx.x;  // over NB*HH*WW = 65536
    if (idx >= NB * HH * WW) return;
    int x = idx & 127;
    int y = (idx >> 7) & 127;
    int n = idx >> 14;
    size_t volbase = (size_t)n * VOX + ((size_t)y << 7) + x;

    float xacc = 0.f, acc = 0.f, tp = 0.f, vp = 0.f;
    for (int k = 0; k < 128; ++k) {
        int z = 127 - k;                      // the flip along D
        size_t off = volbase + ((size_t)z << 14);
        xacc += ds[off];                      // cumsum of flipped ds (DX=1)
        float xc = 20.f * xacc;               // C * x
        float tk = (xc + 1.f) * expf(-xc);
        float vk = vn[off];
        if (k == 0) {
            acc = (1.f - tk) * vk;            // front term
        } else {
            acc += (tp - tk) * (vp + vk) * 0.5f;  // trapezoid
        }
        tp = tk; vp = vk;
    }
    out[idx] = fminf(fmaxf(acc, 0.f), 1.f);
}

extern "C" void kernel_launch(void* const* d_in, const int* in_sizes, int n_in,
                              void* d_out, int out_size, void* d_ws, size_t ws_size,
                              hipStream_t stream) {
    const float* d = (const float*)d_in[0];   // (4,1,128,128,128)
    const float* v = (const float*)d_in[1];   // (4,3,128,128,128)
    float* out = (float*)d_out;               // (4,1,128,128) = 65536

    // normalized 1D Gaussian weights (sigma=1.6), computed in double on host
    GaussW gw;
    {
        double g[7], s = 0.0;
        for (int i = 0; i < 7; ++i) {
            double t = (i - 3) / 1.6;
            g[i] = exp(-t * t / 2.0);
            s += g[i];
        }
        for (int i = 0; i < 7; ++i) gw.w[i] = (float)(g[i] / s);
    }

    float* ws0 = (float*)d_ws;        // ds final
    float* ws1 = ws0 + NVOX;          // scratch
    float* ws2 = ws1 + NVOX;          // vn final

    const int TB = 256;
    const int GB = NVOX / TB;         // 32768

    // ds = smooth(d): z, y, x passes
    smooth_kernel<<<GB, TB, 0, stream>>>(d,   ws1, gw, 14, 16384);
    smooth_kernel<<<GB, TB, 0, stream>>>(ws1, ws2, gw, 7,  128);
    smooth_kernel<<<GB, TB, 0, stream>>>(ws2, ws0, gw, 0,  1);

    // vn = |curl(v)| then smooth
    curlnorm_kernel<<<GB, TB, 0, stream>>>(v, ws1);
    smooth_kernel<<<GB, TB, 0, stream>>>(ws1, ws2, gw, 14, 16384);
    smooth_kernel<<<GB, TB, 0, stream>>>(ws2, ws1, gw, 7,  128);
    smooth_kernel<<<GB, TB, 0, stream>>>(ws1, ws2, gw, 0,  1);

    // final render reduction
    render_kernel<<<(NB * HH * WW) / TB, TB, 0, stream>>>(ws0, ws2, out);
}

// Round 2
// 278.172 us; speedup vs baseline: 1.5171x; 1.5171x over previous
//
#include <hip/hip_runtime.h>
#include <math.h>

#define NB 4
#define DD 128
#define HH 128
#define WW 128
#define VOX (DD*HH*WW)          // 2097152 = 2^21
#define NVOX (NB*VOX)           // 8388608
#define ROLL 8                  // outputs per thread along conv axis
#define NTHR (NVOX/ROLL)        // 1048576

struct GaussW { float w[7]; };

// Register-rolling 7-tap 1D conv: each thread computes ROLL consecutive
// outputs along the axis, loading ROLL+6 inputs once (1.75 loads/output
// instead of 7). shift: bit position of the axis in the linear index
// (x=0, y=7, z=14). Template so stride/shift const-fold.
template <int SHIFT>
__global__ void smooth_roll_kernel(const float* __restrict__ in, float* __restrict__ out,
                                   GaussW gw) {
    const int stride = 1 << SHIFT;
    int t = blockIdx.x * blockDim.x + threadIdx.x;
    if (t >= NTHR) return;
    int low  = t & (stride - 1);          // bits below axis
    int rest = t >> SHIFT;
    int cblk = rest & 15;                 // which 8-block along axis (128/8=16)
    int hi   = rest >> 4;                 // bits above axis
    int c0   = cblk * ROLL;
    // linear index of (hi, c, low): (hi << (SHIFT+7)) | (c << SHIFT) | low
    size_t base = ((size_t)hi << (SHIFT + 7)) | (size_t)low;

    float r[ROLL + 6];
#pragma unroll
    for (int j = 0; j < ROLL + 6; ++j) {
        int cc = c0 - 3 + j;
        r[j] = (cc >= 0 && cc < 128) ? in[base + ((size_t)cc << SHIFT)] : 0.f;
    }
#pragma unroll
    for (int i = 0; i < ROLL; ++i) {
        float acc = 0.f;
#pragma unroll
        for (int k = 0; k < 7; ++k) acc += gw.w[k] * r[i + k];
        out[base + ((size_t)(c0 + i) << SHIFT)] = acc;
    }
}

// forward diff with duplicated last element (matches jnp.diff + concat(last))
__device__ __forceinline__ float fd(const float* __restrict__ f, int base, int c, int stride) {
    int ip = (c < 127) ? base + stride : base;
    int im = (c < 127) ? base          : base - stride;
    return f[ip] - f[im];
}

// vn = |curl(v)|, v layout (N,3,D,H,W)
__global__ void curlnorm_kernel(const float* __restrict__ v, float* __restrict__ vn) {
    int idx = blockIdx.x * blockDim.x + threadIdx.x;
    if (idx >= NVOX) return;
    int x = idx & 127;
    int y = (idx >> 7) & 127;
    int z = (idx >> 14) & 127;
    int n = idx >> 21;
    const float* u  = v + (size_t)n * 3 * VOX;
    const float* vv = u + VOX;
    const float* w  = vv + VOX;
    int base = idx & (VOX - 1);

    // axes of (N,D,H,W): axis1=D(z, stride 16384), axis2=H(y, stride 128), axis3=W(x, stride 1)
    float cu = fd(w,  base, y, 128)   - fd(vv, base, z, 16384); // dw/dy - dv/dz
    float cv = fd(u,  base, z, 16384) - fd(w,  base, x, 1);     // du/dz - dw/dx
    float cw = fd(vv, base, x, 1)     - fd(u,  base, y, 128);   // dv/dx - du/dy
    vn[idx] = sqrtf(cu * cu + cv * cv + cw * cw);
}

// Per (n,y,x) column: flip along z, cumsum -> transmittance, trapezoid integrate, clip.
__global__ void render_kernel(const float* __restrict__ ds, const float* __restrict__ vn,
                              float* __restrict__ out) {
    int idx = blockIdx.x * blockDim.x + threadIdx.x;  // over NB*HH*WW = 65536
    if (idx >= NB * HH * WW) return;
    int x = idx & 127;
    int y = (idx >> 7) & 127;
    int n = idx >> 14;
    size_t volbase = (size_t)n * VOX + ((size_t)y << 7) + x;

    float xacc = 0.f, acc = 0.f, tp = 0.f, vp = 0.f;
    for (int k = 0; k < 128; ++k) {
        int z = 127 - k;                      // the flip along D
        size_t off = volbase + ((size_t)z << 14);
        xacc += ds[off];                      // cumsum of flipped ds (DX=1)
        float xc = 20.f * xacc;               // C * x
        float tk = (xc + 1.f) * expf(-xc);
        float vk = vn[off];
        if (k == 0) {
            acc = (1.f - tk) * vk;            // front term
        } else {
            acc += (tp - tk) * (vp + vk) * 0.5f;  // trapezoid
        }
        tp = tk; vp = vk;
    }
    out[idx] = fminf(fmaxf(acc, 0.f), 1.f);
}

extern "C" void kernel_launch(void* const* d_in, const int* in_sizes, int n_in,
                              void* d_out, int out_size, void* d_ws, size_t ws_size,
                              hipStream_t stream) {
    const float* d = (const float*)d_in[0];   // (4,1,128,128,128)
    const float* v = (const float*)d_in[1];   // (4,3,128,128,128)
    float* out = (float*)d_out;               // (4,1,128,128) = 65536

    // normalized 1D Gaussian weights (sigma=1.6), computed in double on host
    GaussW gw;
    {
        double g[7], s = 0.0;
        for (int i = 0; i < 7; ++i) {
            double t = (i - 3) / 1.6;
            g[i] = exp(-t * t / 2.0);
            s += g[i];
        }
        for (int i = 0; i < 7; ++i) gw.w[i] = (float)(g[i] / s);
    }

    float* ws0 = (float*)d_ws;        // ds final
    float* ws1 = ws0 + NVOX;          // scratch
    float* ws2 = ws1 + NVOX;          // vn final

    const int TB = 256;
    const int GR = NTHR / TB;         // 4096 blocks for rolled smooth
    const int GB = NVOX / TB;         // 32768 blocks for curl

    // ds = smooth(d): z, y, x passes (register-rolled)
    smooth_roll_kernel<14><<<GR, TB, 0, stream>>>(d,   ws1, gw);
    smooth_roll_kernel<7> <<<GR, TB, 0, stream>>>(ws1, ws2, gw);
    smooth_roll_kernel<0> <<<GR, TB, 0, stream>>>(ws2, ws0, gw);

    // vn = |curl(v)| then smooth
    curlnorm_kernel<<<GB, TB, 0, stream>>>(v, ws1);
    smooth_roll_kernel<14><<<GR, TB, 0, stream>>>(ws1, ws2, gw);
    smooth_roll_kernel<7> <<<GR, TB, 0, stream>>>(ws2, ws1, gw);
    smooth_roll_kernel<0> <<<GR, TB, 0, stream>>>(ws1, ws2, gw);

    // final render reduction
    render_kernel<<<(NB * HH * WW) / TB, TB, 0, stream>>>(ws0, ws2, out);
}